// Round 28
// baseline (63.434 us; speedup 1.0000x reference)
//
#include <hip/hip_runtime.h>
#include <math.h>

#define BATCH 2048

typedef __attribute__((ext_vector_type(4))) int i32x4;
typedef __attribute__((ext_vector_type(16))) int i32x16;
typedef __attribute__((ext_vector_type(2))) float f32x2;

__device__ __forceinline__ int sdot4(int a, int b, int c) {
    return __builtin_amdgcn_sdot4(a, b, c, false);
}

__device__ __forceinline__ float fsign(float v) {
    return v > 0.f ? 1.f : (v < 0.f ? -1.f : 0.f);
}

// act swizzle (T2): flips addr bits 4-6 by pixel bits 2-4; bijective on [0,9248),
// keeps 16B chunks intact, independent of the low 5 bits (oc).
__device__ __forceinline__ int aswz(int off) {
    return off ^ (((off >> 7) & 7) << 4);
}

// w2 [64][32][5][5] -> w2p [25 tap][2 khalf][64 oc][16 ic] (sign)
__global__ void prep_w2(const float* __restrict__ w2, signed char* __restrict__ w2p) {
    int i = blockIdx.x * 256 + threadIdx.x;   // 51200
    int tap = i >> 11;
    int r = i & 2047;
    int half = r >> 10;
    int r2 = r & 1023;
    int oc = r2 >> 4, j = r2 & 15;
    int ic = half * 16 + j;
    float v = w2[(oc * 32 + ic) * 25 + tap];
    w2p[i] = v > 0.f ? 1 : (v < 0.f ? -1 : 0);
}

// K12: conv1(+BN+sign+pool) fused into conv2 MFMA. Block = 8 images, 12 waves,
// 1 block/CU. Phase0: zero act LDS, stage weights (linear) + 8 images of x
// (linear float4). Phase1: r27's sliding-window pk-FMA conv from LDS x,
// byte-writes into swizzled act LDS (bit-identical chains). Phase2: r27 MFMA.
// Tail: wf1/wf2 binarize slice (consumed only by k3/k4 -> stream-safe).
// LDS 150,272 B = act 73,984 | w 51,200 | xs 25,088. act1 global is GONE.
#define K2_IMG_STRIDE 9248          // 17*17*32
#define K2_WOFF 73984               // 8*9248
#define K2_XOFF 125184              // + 51200
__global__ __launch_bounds__(768) void k12_fused(
        const float* __restrict__ x,
        const float* __restrict__ w1, const float* __restrict__ b1,
        const float* __restrict__ g1, const float* __restrict__ be1,
        const float* __restrict__ m1, const float* __restrict__ v1,
        const signed char* __restrict__ w2p,
        const float* __restrict__ b2, const float* __restrict__ g2,
        const float* __restrict__ be2, const float* __restrict__ m2,
        const float* __restrict__ v2,
        const float* __restrict__ wf1, const float* __restrict__ wf2,
        signed char* __restrict__ wf1s, signed char* __restrict__ wf2p,
        signed char* __restrict__ act2) {
    __shared__ __align__(16) signed char smem[150272];
    int tid = threadIdx.x;
    int b0 = blockIdx.x * 8;

    // ---- phase 0: zero act region; stage weights + x (all linear) ----
    {
        i32x4 z4 = {0, 0, 0, 0};
        i32x4* s4 = (i32x4*)smem;
        for (int i = tid; i < 4624; i += 768) s4[i] = z4;
        const i32x4* wsrc = (const i32x4*)w2p;
        i32x4* w4 = (i32x4*)(smem + K2_WOFF);
        for (int i = tid; i < 3200; i += 768) w4[i] = wsrc[i];
        const float4* xsrc = (const float4*)(x + (size_t)b0 * 784);
        float4* xdst = (float4*)(smem + K2_XOFF);
        for (int i = tid; i < 1568; i += 768) xdst[i] = xsrc[i];
    }
    __syncthreads();

    // ---- phase 1: conv1 + BN + sign + pool2 -> act LDS bytes (swizzled) ----
    {
        const float* xs = (const float*)(smem + K2_XOFF);
        int oc = tid & 31;              // constant across iterations (768%32==0)
        int rbase = tid >> 5;           // 0..23
        float sw[9];
#pragma unroll
        for (int i = 0; i < 9; i++) sw[i] = fsign(w1[oc * 9 + i]);
        float bias = b1[oc], m = m1[oc];
        float sc = g1[oc] / sqrtf(v1[oc] + 1e-5f), bb = be1[oc];
#pragma unroll
        for (int it = 0; it < 5; ++it) {
            int r = rbase + 24 * it;    // 0..103 = 8 img x 13 py
            if (r < 104) {
                int img = r / 13, py = r - img * 13;
                const float* rowp = xs + img * 784 + py * 56;   // conv row 2py
                signed char* abase = smem + img * K2_IMG_STRIDE;
                int p32base = ((py + 2) * 17 + 2) * 32;
                f32x2 lo[4], hi[4];
#pragma unroll
                for (int dy = 0; dy < 4; dy++) {
                    lo[dy] = *(const f32x2*)(rowp + dy * 28);      // cols 0,1
                    hi[dy] = *(const f32x2*)(rowp + dy * 28 + 2);  // cols 2,3
                }
#pragma unroll
                for (int px = 0; px < 13; px++) {
                    f32x2 pm[4];
#pragma unroll
                    for (int dy = 0; dy < 4; dy++) {
                        pm[dy].x = lo[dy].y;          // cols 2px+1, 2px+2
                        pm[dy].y = hi[dy].x;
                    }
                    f32x2 a01 = {0.f, 0.f};   // dyp = 0 (rows 0..2)
                    f32x2 a23 = {0.f, 0.f};   // dyp = 1 (rows 1..3)
#pragma unroll
                    for (int ky = 0; ky < 3; ky++) {
                        a01 += lo[ky] * sw[ky * 3 + 0];
                        a01 += pm[ky] * sw[ky * 3 + 1];
                        a01 += hi[ky] * sw[ky * 3 + 2];
                        a23 += lo[ky + 1] * sw[ky * 3 + 0];
                        a23 += pm[ky + 1] * sw[ky * 3 + 1];
                        a23 += hi[ky + 1] * sw[ky * 3 + 2];
                    }
                    float maxacc = fmaxf(fmaxf(a01.x, a01.y), fmaxf(a23.x, a23.y));
                    float bn = (maxacc + bias - m) * sc + bb;   // same assoc as r27
                    abase[aswz(p32base + px * 32 + oc)] = (signed char)fsign(bn);
                    if (px < 12) {
#pragma unroll
                        for (int dy = 0; dy < 4; dy++) {
                            lo[dy] = hi[dy];          // rotation
                            hi[dy] = *(const f32x2*)(rowp + dy * 28 + 2 * px + 4);
                        }
                    }
                }
            }
        }
    }
    __syncthreads();

    // ---- phase 2: conv2 MFMA (r27 verbatim) ----
    int wave = tid >> 6, lane = tid & 63;
    int lrow = lane & 31, kh = lane >> 5;
    const signed char* wbase = smem + K2_WOFF + kh * 1024 + lrow * 16;

    const signed char* aimg[3];
    int pixbase[3];
#pragma unroll
    for (int t = 0; t < 3; ++t) {
        int mt = wave * 3 + t;                // 0..35
        int m = mt * 32 + lrow;
        int q = m >> 2, j = m & 3;
        int img = q / 36, qq = q - img * 36;
        int oy = 2 * (qq / 6) + (j >> 1);
        int ox = 2 * (qq - (qq / 6) * 6) + (j & 1);
        aimg[t] = smem + img * K2_IMG_STRIDE;
        pixbase[t] = oy * 17 + ox;
    }

    i32x16 acc[3][2] = {};
#pragma unroll 5
    for (int tap = 0; tap < 25; ++tap) {
        int ky = tap / 5, kx = tap - (tap / 5) * 5;
        i32x4 w0 = *(const i32x4*)(wbase + tap * 2048);        // oc = lrow
        i32x4 w1v = *(const i32x4*)(wbase + tap * 2048 + 512); // oc = 32+lrow
#pragma unroll
        for (int t = 0; t < 3; ++t) {
            int off = (pixbase[t] + ky * 17 + kx) * 32 + kh * 16;
            i32x4 a = *(const i32x4*)(aimg[t] + aswz(off));
            acc[t][0] = __builtin_amdgcn_mfma_i32_32x32x32_i8(a, w0, acc[t][0], 0, 0, 0);
            acc[t][1] = __builtin_amdgcn_mfma_i32_32x32x32_i8(a, w1v, acc[t][1], 0, 0, 0);
        }
    }
    __syncthreads();   // all LDS A/W reads done -> act region reusable

    float bi[2], mm2[2], sc2[2], bb2[2];
#pragma unroll
    for (int h = 0; h < 2; ++h) {
        int oc = h * 32 + lrow;
        bi[h] = b2[oc]; mm2[h] = m2[oc];
        sc2[h] = g2[oc] / sqrtf(v2[oc] + 1e-5f); bb2[h] = be2[oc];
    }
#pragma unroll
    for (int t = 0; t < 3; ++t) {
        int mt = wave * 3 + t;
#pragma unroll
        for (int h = 0; h < 2; ++h) {
            int oc = h * 32 + lrow;
#pragma unroll
            for (int g = 0; g < 4; g++) {
                int qo = mt * 8 + kh + 2 * g;     // pool cell 0..287 (8 images)
                int imo = qo / 36, qqo = qo - imo * 36;
                float best = -2.f;
#pragma unroll
                for (int jj = 0; jj < 4; jj++) {
                    float z = (float)acc[t][h][g * 4 + jj] + bi[h];
                    float bn = (z - mm2[h]) * sc2[h] + bb2[h];
                    best = fmaxf(best, fsign(bn));
                }
                smem[imo * 2304 + oc * 36 + qqo] = (signed char)best;
            }
        }
    }
    __syncthreads();
    {
        const i32x4* s4o = (const i32x4*)smem;
        i32x4* dst = (i32x4*)(act2 + (size_t)b0 * 2304);
        for (int i = tid; i < 1152; i += 768) dst[i] = s4o[i];
    }

    // ---- tail: wf1/wf2 binarize slice (for k3/k4; stream-order safe) ----
    {
        int base = blockIdx.x * 9256;             // 256*9256 = 2,369,536
        for (int t = tid; t < 9256; t += 768) {
            int i = base + t;
            if (i < 2359296) {
                float v = wf1[i];
                wf1s[i] = v > 0.f ? 1 : (v < 0.f ? -1 : 0);
            } else {
                int ii = i - 2359296;             // < 10240
                float v = wf2[ii];
                wf2p[ii] = v > 0.f ? 1 : (v < 0.f ? -1 : 0);
            }
        }
    }
}

// K3: fc1 as LDS-tiled MFMA i8 GEMM 2048x1024x2304. (r27 verbatim)
#define K3A_SEG 2064                // 128*16 + 16 pad
#define K3B_SEG 1040                // 64*16 + 16 pad
#define K3_BOFF 16512               // 8 * 2064
__global__ __launch_bounds__(256) void k3_mfma(
        const signed char* __restrict__ act2, const signed char* __restrict__ wf1s,
        const float* __restrict__ bf1, const float* __restrict__ gf1,
        const float* __restrict__ bef1, const float* __restrict__ mf1,
        const float* __restrict__ vf1, signed char* __restrict__ act3) {
    __shared__ __align__(16) signed char s[K3_BOFF + 8 * K3B_SEG];  // 24832
    int tid = threadIdx.x;
    int bid = blockIdx.x;
    int tn = bid & 15, tm = bid >> 4;

    const signed char* Ab = act2 + (size_t)tm * 128 * 2304;
    const signed char* Bb = wf1s + (size_t)tn * 64 * 2304;
    size_t gA[4]; int lwA[4];
#pragma unroll
    for (int i = 0; i < 4; i++) {
        int e = tid + 256 * i, row = e >> 3, sg = (e + row) & 7;
        gA[i] = (size_t)row * 2304 + sg * 16;
        lwA[i] = sg * K3A_SEG + row * 16;
    }
    size_t gB[2]; int lwB[2];
#pragma unroll
    for (int i = 0; i < 2; i++) {
        int e = tid + 256 * i, row = e >> 3, sg = (e + row) & 7;
        gB[i] = (size_t)row * 2304 + sg * 16;
        lwB[i] = K3_BOFF + sg * K3B_SEG + row * 16;
    }

    i32x4 ra[4], rb[2];
#pragma unroll
    for (int i = 0; i < 4; i++) ra[i] = *(const i32x4*)(Ab + gA[i]);
#pragma unroll
    for (int i = 0; i < 2; i++) rb[i] = *(const i32x4*)(Bb + gB[i]);

    int l = tid & 63, wid = tid >> 6;
    int lrow = l & 31, kh = l >> 5;
    int raddrA = kh * K3A_SEG + (wid * 32 + lrow) * 16;
    int raddrB0 = K3_BOFF + kh * K3B_SEG + lrow * 16;
    int raddrB1 = raddrB0 + 32 * 16;

    i32x16 acc0 = {0};
    i32x16 acc1 = {0};
    for (int t = 0; t < 18; ++t) {
        if (t) __syncthreads();
#pragma unroll
        for (int i = 0; i < 4; i++) *(i32x4*)(s + lwA[i]) = ra[i];
#pragma unroll
        for (int i = 0; i < 2; i++) *(i32x4*)(s + lwB[i]) = rb[i];
        if (t < 17) {
            size_t ko = (size_t)(t + 1) * 128;
#pragma unroll
            for (int i = 0; i < 4; i++) ra[i] = *(const i32x4*)(Ab + gA[i] + ko);
#pragma unroll
            for (int i = 0; i < 2; i++) rb[i] = *(const i32x4*)(Bb + gB[i] + ko);
        }
        __syncthreads();
#pragma unroll
        for (int ks = 0; ks < 4; ++ks) {
            i32x4 a  = *(const i32x4*)(s + raddrA + ks * 2 * K3A_SEG);
            i32x4 b0 = *(const i32x4*)(s + raddrB0 + ks * 2 * K3B_SEG);
            i32x4 b1 = *(const i32x4*)(s + raddrB1 + ks * 2 * K3B_SEG);
            acc0 = __builtin_amdgcn_mfma_i32_32x32x32_i8(a, b0, acc0, 0, 0, 0);
            acc1 = __builtin_amdgcn_mfma_i32_32x32x32_i8(a, b1, acc1, 0, 0, 0);
        }
    }

    int col0 = tn * 64 + lrow;
    int col1 = col0 + 32;
    float bi0 = bf1[col0], m0 = mf1[col0];
    float sc0 = gf1[col0] / sqrtf(vf1[col0] + 1e-5f), bb0 = bef1[col0];
    float bi1 = bf1[col1], m1 = mf1[col1];
    float sc1 = gf1[col1] / sqrtf(vf1[col1] + 1e-5f), bb1 = bef1[col1];
    __syncthreads();   // K-loop reads of s done -> reuse as output tile [128][64]
#pragma unroll
    for (int r = 0; r < 16; r++) {
        int rowl = wid * 32 + (r & 3) + 8 * (r >> 2) + 4 * kh;
        float bn0 = ((float)acc0[r] + bi0 - m0) * sc0 + bb0;
        float bn1 = ((float)acc1[r] + bi1 - m1) * sc1 + bb1;
        s[rowl * 64 + lrow] = (signed char)fsign(bn0);
        s[rowl * 64 + lrow + 32] = (signed char)fsign(bn1);
    }
    __syncthreads();
    for (int i = tid; i < 512; i += 256) {
        int rl = i >> 2, c16 = i & 3;
        *(i32x4*)(act3 + (size_t)(tm * 128 + rl) * 1024 + tn * 64 + c16 * 16) =
            *(const i32x4*)(s + i * 16);
    }
}

// K4: fc2 (1024->10) + bias + BN + log_softmax. One wave per image. (unchanged)
__global__ void k4_fc2(const signed char* __restrict__ act3, const signed char* __restrict__ swf2,
                       const float* __restrict__ bf2, const float* __restrict__ gf2,
                       const float* __restrict__ bef2, const float* __restrict__ mf2,
                       const float* __restrict__ vf2, float* __restrict__ out) {
    int wid = (blockIdx.x * 256 + threadIdx.x) >> 6;
    int lane = threadIdx.x & 63;
    if (wid >= BATCH) return;
    const int* hd = (const int*)act3 + (size_t)wid * 256;
    const int* wd = (const int*)swf2;
    int acc[10];
#pragma unroll
    for (int o = 0; o < 10; o++) acc[o] = 0;
#pragma unroll
    for (int i = 0; i < 4; i++) {
        int k4 = i * 64 + lane;
        int hv = hd[k4];
#pragma unroll
        for (int o = 0; o < 10; o++)
            acc[o] = sdot4(hv, wd[o * 256 + k4], acc[o]);
    }
#pragma unroll
    for (int o = 0; o < 10; o++)
#pragma unroll
        for (int s = 32; s > 0; s >>= 1) acc[o] += __shfl_xor(acc[o], s);
    if (lane == 0) {
        float logit[10];
        float mx = -1e30f;
#pragma unroll
        for (int o = 0; o < 10; o++) {
            float z = (float)acc[o] + bf2[o];
            float bn = (z - mf2[o]) * (gf2[o] / sqrtf(vf2[o] + 1e-5f)) + bef2[o];
            logit[o] = bn;
            mx = fmaxf(mx, bn);
        }
        float s = 0.f;
#pragma unroll
        for (int o = 0; o < 10; o++) s += expf(logit[o] - mx);
        float lse = mx + logf(s);
#pragma unroll
        for (int o = 0; o < 10; o++) out[(size_t)wid * 10 + o] = logit[o] - lse;
    }
}

extern "C" void kernel_launch(void* const* d_in, const int* in_sizes, int n_in,
                              void* d_out, int out_size, void* d_ws, size_t ws_size,
                              hipStream_t stream) {
    const float* x   = (const float*)d_in[0];
    const float* w1  = (const float*)d_in[1];
    const float* b1  = (const float*)d_in[2];
    const float* g1  = (const float*)d_in[3];
    const float* be1 = (const float*)d_in[4];
    const float* m1  = (const float*)d_in[5];
    const float* v1  = (const float*)d_in[6];
    const float* w2  = (const float*)d_in[7];
    const float* b2  = (const float*)d_in[8];
    const float* g2  = (const float*)d_in[9];
    const float* be2 = (const float*)d_in[10];
    const float* m2  = (const float*)d_in[11];
    const float* v2  = (const float*)d_in[12];
    const float* wf1 = (const float*)d_in[13];
    const float* bf1 = (const float*)d_in[14];
    const float* gf1 = (const float*)d_in[15];
    const float* bef1= (const float*)d_in[16];
    const float* mf1 = (const float*)d_in[17];
    const float* vf1 = (const float*)d_in[18];
    const float* wf2 = (const float*)d_in[19];
    const float* bf2 = (const float*)d_in[20];
    const float* gf2 = (const float*)d_in[21];
    const float* bef2= (const float*)d_in[22];
    const float* mf2 = (const float*)d_in[23];
    const float* vf2 = (const float*)d_in[24];
    float* out = (float*)d_out;

    // ws layout (all int8)
    char* ws = (char*)d_ws;
    signed char* act2 = (signed char*)ws;                  // 2048*2304     =  4,718,592
    signed char* act3 = act2 + 4718592;                    // 2048*1024     =  2,097,152
    signed char* w2p  = act3 + 2097152;                    // 25*2*64*16    =     51,200
    signed char* wf1s = w2p + 51200;                       // 1024*2304     =  2,359,296
    signed char* wf2p = wf1s + 2359296;                    // 10*1024       =     10,240

    prep_w2<<<200, 256, 0, stream>>>(w2, w2p);

    k12_fused<<<256, 768, 0, stream>>>(x, w1, b1, g1, be1, m1, v1,
                                       w2p, b2, g2, be2, m2, v2,
                                       wf1, wf2, wf1s, wf2p, act2);

    k3_mfma<<<256, 256, 0, stream>>>(act2, wf1s, bf1, gf1, bef1, mf1, vf1, act3);

    k4_fc2<<<512, 256, 0, stream>>>(act3, wf2p, bf2, gf2, bef2, mf2, vf2, out);
}

// Round 29
// 60.514 us; speedup vs baseline: 1.0483x; 1.0483x over previous
//
#include <hip/hip_runtime.h>
#include <math.h>

#define BATCH 2048

typedef __attribute__((ext_vector_type(4))) int i32x4;
typedef __attribute__((ext_vector_type(16))) int i32x16;
typedef __attribute__((ext_vector_type(2))) float f32x2;

__device__ __forceinline__ int sdot4(int a, int b, int c) {
    return __builtin_amdgcn_sdot4(a, b, c, false);
}

__device__ __forceinline__ float fsign(float v) {
    return v > 0.f ? 1.f : (v < 0.f ? -1.f : 0.f);
}

// act swizzle (T2): flips addr bits 4-6 by pixel bits 2-4; bijective on [0,9248),
// keeps 16B chunks intact, independent of the low 5 bits (oc).
__device__ __forceinline__ int aswz(int off) {
    return off ^ (((off >> 7) & 7) << 4);
}

// K1 + prep fused. 2 images/block, 512 threads: halves per-image fixed phases
// (prep slice, staging, border, copy-out). Conv = r27's sliding-window pk-FMA
// from LDS x -> bit-identical output. LDS 36 KB -> 4 blocks/CU.
__global__ __launch_bounds__(512) void k1_prep(
        const float* __restrict__ x,
        const float* __restrict__ w1, const float* __restrict__ b1,
        const float* __restrict__ g1, const float* __restrict__ be1,
        const float* __restrict__ m1, const float* __restrict__ v1,
        const float* __restrict__ w2, const float* __restrict__ wf1,
        const float* __restrict__ wf2,
        signed char* __restrict__ w2p, signed char* __restrict__ wf1s,
        signed char* __restrict__ wf2p, signed char* __restrict__ act1) {
    __shared__ __align__(16) float xs[1568];           // 2 images
    __shared__ __align__(16) signed char lact[10816];  // 2 x [169][32]
    int blk = blockIdx.x, tid = threadIdx.x;
    int b0 = blk * 2;

    // stage 2 images (coalesced float4)
    if (tid < 392) ((float4*)xs)[tid] = ((const float4*)(x + (size_t)b0 * 784))[tid];

    // ---- prep slice: 2364 elements (1024 blocks x 2364 = 2,420,736) ----
    {
        int base = blk * 2364;
        for (int t = tid; t < 2364; t += 512) {
            int i = base + t;
            if (i < 2359296) {                  // wf1 sign (natural layout)
                float v = wf1[i];
                wf1s[i] = v > 0.f ? 1 : (v < 0.f ? -1 : 0);
            } else if (i < 2359296 + 51200) {   // w2p [tap][half][oc][16]
                int ii = i - 2359296;
                int tap = ii >> 11;
                int r = ii & 2047;
                int half = r >> 10;
                int r2 = r & 1023;
                int oc = r2 >> 4, j = r2 & 15;
                int ic = half * 16 + j;
                float v = w2[(oc * 32 + ic) * 25 + tap];
                w2p[ii] = v > 0.f ? 1 : (v < 0.f ? -1 : 0);
            } else {                            // wf2 sign
                int ii = i - 2359296 - 51200;
                float v = wf2[ii];
                wf2p[ii] = v > 0.f ? 1 : (v < 0.f ? -1 : 0);
            }
        }
    }

    // zero the border pixels of both images (480 x 16B chunks)
    i32x4 z4 = {0, 0, 0, 0};
    if (tid < 480) {
        int img = tid / 240, ii = tid - img * 240;
        int pi = ii >> 1, half = ii & 1;
        int p;
        if (pi < 34) p = pi;                       // rows 0-1
        else if (pi < 68) p = 255 + (pi - 34);     // rows 15-16
        else {                                     // rows 2-14, cols 0,1,15,16
            int j2 = pi - 68;
            int row = 2 + (j2 >> 2), c = j2 & 3;
            int col = (c < 2) ? c : 13 + c;        // 0,1,15,16
            p = row * 17 + col;
        }
        *(i32x4*)(act1 + (size_t)(b0 + img) * 9248 + aswz(p * 32 + half * 16)) = z4;
    }
    __syncthreads();   // xs ready

    // ---- conv1 + BN + sign + pool2 (sliding-window, packed-FMA, LDS x) ----
    {
        int oc = tid & 31, slot = tid >> 5;   // 16 slots
        float sw[9];
#pragma unroll
        for (int i = 0; i < 9; i++) sw[i] = fsign(w1[oc * 9 + i]);
        float bias = b1[oc], m = m1[oc];
        float sc = g1[oc] / sqrtf(v1[oc] + 1e-5f), bb = be1[oc];
#pragma unroll
        for (int it = 0; it < 2; ++it) {
            int r = slot + 16 * it;           // 0..25 = 2 img x 13 py
            if (r < 26) {
                int img = (r >= 13) ? 1 : 0;
                int py = r - img * 13;
                const float* rowp = xs + img * 784 + py * 56;   // conv row 2py
                signed char* lrow = lact + img * 5408 + py * 416 + oc;

                f32x2 lo[4], hi[4];
#pragma unroll
                for (int dy = 0; dy < 4; dy++) {
                    lo[dy] = *(const f32x2*)(rowp + dy * 28);      // cols 0,1
                    hi[dy] = *(const f32x2*)(rowp + dy * 28 + 2);  // cols 2,3
                }
#pragma unroll
                for (int px = 0; px < 13; px++) {
                    f32x2 pm[4];
#pragma unroll
                    for (int dy = 0; dy < 4; dy++) {
                        pm[dy].x = lo[dy].y;          // cols 2px+1, 2px+2
                        pm[dy].y = hi[dy].x;
                    }
                    f32x2 a01 = {0.f, 0.f};   // dyp = 0 (rows 0..2)
                    f32x2 a23 = {0.f, 0.f};   // dyp = 1 (rows 1..3)
#pragma unroll
                    for (int ky = 0; ky < 3; ky++) {
                        a01 += lo[ky] * sw[ky * 3 + 0];
                        a01 += pm[ky] * sw[ky * 3 + 1];
                        a01 += hi[ky] * sw[ky * 3 + 2];
                        a23 += lo[ky + 1] * sw[ky * 3 + 0];
                        a23 += pm[ky + 1] * sw[ky * 3 + 1];
                        a23 += hi[ky + 1] * sw[ky * 3 + 2];
                    }
                    float maxacc = fmaxf(fmaxf(a01.x, a01.y), fmaxf(a23.x, a23.y));
                    float bn = (maxacc + bias - m) * sc + bb;  // same assoc as r27
                    lrow[px * 32] = (signed char)fsign(bn);
                    if (px < 12) {
#pragma unroll
                        for (int dy = 0; dy < 4; dy++) {
                            lo[dy] = hi[dy];          // rotation
                            hi[dy] = *(const f32x2*)(rowp + dy * 28 + 2 * px + 4);
                        }
                    }
                }
            }
        }
    }
    __syncthreads();

    // ---- copy-out: pad+aswz mapping, coalesced 16B global writes ----
    for (int i = tid; i < 676; i += 512) {
        int img = i / 338, rr = i - img * 338;
        int pix = rr >> 1, half = rr & 1;
        int py2 = pix / 13, px2 = pix - py2 * 13;
        int p = (py2 + 2) * 17 + (px2 + 2);
        *(i32x4*)(act1 + (size_t)(b0 + img) * 9248 + aswz(p * 32 + half * 16)) =
            *(const i32x4*)(lact + img * 5408 + pix * 32 + half * 16);
    }
}

// K2: conv2 implicit-GEMM MFMA i8. Block = 8 images, 12 waves (768 thr).
// Grid = 256 = 1 block/CU. Staging = pure linear copy. (r27 verbatim)
#define K2_IMG_STRIDE 9248          // 17*17*32
#define K2_WOFF 73984               // 8*9248
__global__ __launch_bounds__(768) void k2_mfma(
        const signed char* __restrict__ act1, const signed char* __restrict__ w2p,
        const float* __restrict__ b2, const float* __restrict__ g2,
        const float* __restrict__ be2, const float* __restrict__ m2,
        const float* __restrict__ v2, signed char* __restrict__ act2) {
    __shared__ __align__(16) signed char smem[125184];
    int tid = threadIdx.x;
    int b0 = blockIdx.x * 8;

    {
        const i32x4* asrc = (const i32x4*)(act1 + (size_t)b0 * 9248);
        i32x4* s4 = (i32x4*)smem;
        for (int i = tid; i < 4624; i += 768) s4[i] = asrc[i];
        const i32x4* wsrc = (const i32x4*)w2p;
        i32x4* w4 = (i32x4*)(smem + K2_WOFF);
        for (int i = tid; i < 3200; i += 768) w4[i] = wsrc[i];
    }
    __syncthreads();

    int wave = tid >> 6, lane = tid & 63;
    int lrow = lane & 31, kh = lane >> 5;
    const signed char* wbase = smem + K2_WOFF + kh * 1024 + lrow * 16;

    const signed char* aimg[3];
    int pixbase[3];
#pragma unroll
    for (int t = 0; t < 3; ++t) {
        int mt = wave * 3 + t;                // 0..35
        int m = mt * 32 + lrow;
        int q = m >> 2, j = m & 3;
        int img = q / 36, qq = q - img * 36;
        int oy = 2 * (qq / 6) + (j >> 1);
        int ox = 2 * (qq - (qq / 6) * 6) + (j & 1);
        aimg[t] = smem + img * K2_IMG_STRIDE;
        pixbase[t] = oy * 17 + ox;
    }

    i32x16 acc[3][2] = {};
#pragma unroll 5
    for (int tap = 0; tap < 25; ++tap) {
        int ky = tap / 5, kx = tap - (tap / 5) * 5;
        i32x4 w0 = *(const i32x4*)(wbase + tap * 2048);        // oc = lrow
        i32x4 w1v = *(const i32x4*)(wbase + tap * 2048 + 512); // oc = 32+lrow
#pragma unroll
        for (int t = 0; t < 3; ++t) {
            int off = (pixbase[t] + ky * 17 + kx) * 32 + kh * 16;
            i32x4 a = *(const i32x4*)(aimg[t] + aswz(off));
            acc[t][0] = __builtin_amdgcn_mfma_i32_32x32x32_i8(a, w0, acc[t][0], 0, 0, 0);
            acc[t][1] = __builtin_amdgcn_mfma_i32_32x32x32_i8(a, w1v, acc[t][1], 0, 0, 0);
        }
    }
    __syncthreads();   // all LDS A/W reads done -> act region reusable

    float bi[2], mm2[2], sc2[2], bb2[2];
#pragma unroll
    for (int h = 0; h < 2; ++h) {
        int oc = h * 32 + lrow;
        bi[h] = b2[oc]; mm2[h] = m2[oc];
        sc2[h] = g2[oc] / sqrtf(v2[oc] + 1e-5f); bb2[h] = be2[oc];
    }
#pragma unroll
    for (int t = 0; t < 3; ++t) {
        int mt = wave * 3 + t;
#pragma unroll
        for (int h = 0; h < 2; ++h) {
            int oc = h * 32 + lrow;
#pragma unroll
            for (int g = 0; g < 4; g++) {
                int qo = mt * 8 + kh + 2 * g;     // pool cell 0..287 (8 images)
                int imo = qo / 36, qqo = qo - imo * 36;
                float best = -2.f;
#pragma unroll
                for (int jj = 0; jj < 4; jj++) {
                    float z = (float)acc[t][h][g * 4 + jj] + bi[h];
                    float bn = (z - mm2[h]) * sc2[h] + bb2[h];
                    best = fmaxf(best, fsign(bn));
                }
                smem[imo * 2304 + oc * 36 + qqo] = (signed char)best;
            }
        }
    }
    __syncthreads();
    {
        const i32x4* s4o = (const i32x4*)smem;
        i32x4* dst = (i32x4*)(act2 + (size_t)b0 * 2304);
        for (int i = tid; i < 1152; i += 768) dst[i] = s4o[i];
    }
}

// K3: fc1 as LDS-tiled MFMA i8 GEMM 2048x1024x2304. (r27 verbatim)
#define K3A_SEG 2064                // 128*16 + 16 pad
#define K3B_SEG 1040                // 64*16 + 16 pad
#define K3_BOFF 16512               // 8 * 2064
__global__ __launch_bounds__(256) void k3_mfma(
        const signed char* __restrict__ act2, const signed char* __restrict__ wf1s,
        const float* __restrict__ bf1, const float* __restrict__ gf1,
        const float* __restrict__ bef1, const float* __restrict__ mf1,
        const float* __restrict__ vf1, signed char* __restrict__ act3) {
    __shared__ __align__(16) signed char s[K3_BOFF + 8 * K3B_SEG];  // 24832
    int tid = threadIdx.x;
    int bid = blockIdx.x;
    int tn = bid & 15, tm = bid >> 4;

    const signed char* Ab = act2 + (size_t)tm * 128 * 2304;
    const signed char* Bb = wf1s + (size_t)tn * 64 * 2304;
    size_t gA[4]; int lwA[4];
#pragma unroll
    for (int i = 0; i < 4; i++) {
        int e = tid + 256 * i, row = e >> 3, sg = (e + row) & 7;
        gA[i] = (size_t)row * 2304 + sg * 16;
        lwA[i] = sg * K3A_SEG + row * 16;
    }
    size_t gB[2]; int lwB[2];
#pragma unroll
    for (int i = 0; i < 2; i++) {
        int e = tid + 256 * i, row = e >> 3, sg = (e + row) & 7;
        gB[i] = (size_t)row * 2304 + sg * 16;
        lwB[i] = K3_BOFF + sg * K3B_SEG + row * 16;
    }

    i32x4 ra[4], rb[2];
#pragma unroll
    for (int i = 0; i < 4; i++) ra[i] = *(const i32x4*)(Ab + gA[i]);
#pragma unroll
    for (int i = 0; i < 2; i++) rb[i] = *(const i32x4*)(Bb + gB[i]);

    int l = tid & 63, wid = tid >> 6;
    int lrow = l & 31, kh = l >> 5;
    int raddrA = kh * K3A_SEG + (wid * 32 + lrow) * 16;
    int raddrB0 = K3_BOFF + kh * K3B_SEG + lrow * 16;
    int raddrB1 = raddrB0 + 32 * 16;

    i32x16 acc0 = {0};
    i32x16 acc1 = {0};
    for (int t = 0; t < 18; ++t) {
        if (t) __syncthreads();
#pragma unroll
        for (int i = 0; i < 4; i++) *(i32x4*)(s + lwA[i]) = ra[i];
#pragma unroll
        for (int i = 0; i < 2; i++) *(i32x4*)(s + lwB[i]) = rb[i];
        if (t < 17) {
            size_t ko = (size_t)(t + 1) * 128;
#pragma unroll
            for (int i = 0; i < 4; i++) ra[i] = *(const i32x4*)(Ab + gA[i] + ko);
#pragma unroll
            for (int i = 0; i < 2; i++) rb[i] = *(const i32x4*)(Bb + gB[i] + ko);
        }
        __syncthreads();
#pragma unroll
        for (int ks = 0; ks < 4; ++ks) {
            i32x4 a  = *(const i32x4*)(s + raddrA + ks * 2 * K3A_SEG);
            i32x4 b0 = *(const i32x4*)(s + raddrB0 + ks * 2 * K3B_SEG);
            i32x4 b1 = *(const i32x4*)(s + raddrB1 + ks * 2 * K3B_SEG);
            acc0 = __builtin_amdgcn_mfma_i32_32x32x32_i8(a, b0, acc0, 0, 0, 0);
            acc1 = __builtin_amdgcn_mfma_i32_32x32x32_i8(a, b1, acc1, 0, 0, 0);
        }
    }

    int col0 = tn * 64 + lrow;
    int col1 = col0 + 32;
    float bi0 = bf1[col0], m0 = mf1[col0];
    float sc0 = gf1[col0] / sqrtf(vf1[col0] + 1e-5f), bb0 = bef1[col0];
    float bi1 = bf1[col1], m1 = mf1[col1];
    float sc1 = gf1[col1] / sqrtf(vf1[col1] + 1e-5f), bb1 = bef1[col1];
    __syncthreads();   // K-loop reads of s done -> reuse as output tile [128][64]
#pragma unroll
    for (int r = 0; r < 16; r++) {
        int rowl = wid * 32 + (r & 3) + 8 * (r >> 2) + 4 * kh;
        float bn0 = ((float)acc0[r] + bi0 - m0) * sc0 + bb0;
        float bn1 = ((float)acc1[r] + bi1 - m1) * sc1 + bb1;
        s[rowl * 64 + lrow] = (signed char)fsign(bn0);
        s[rowl * 64 + lrow + 32] = (signed char)fsign(bn1);
    }
    __syncthreads();
    for (int i = tid; i < 512; i += 256) {
        int rl = i >> 2, c16 = i & 3;
        *(i32x4*)(act3 + (size_t)(tm * 128 + rl) * 1024 + tn * 64 + c16 * 16) =
            *(const i32x4*)(s + i * 16);
    }
}

// K4: fc2 (1024->10) + bias + BN + log_softmax. One wave per image. (unchanged)
__global__ void k4_fc2(const signed char* __restrict__ act3, const signed char* __restrict__ swf2,
                       const float* __restrict__ bf2, const float* __restrict__ gf2,
                       const float* __restrict__ bef2, const float* __restrict__ mf2,
                       const float* __restrict__ vf2, float* __restrict__ out) {
    int wid = (blockIdx.x * 256 + threadIdx.x) >> 6;
    int lane = threadIdx.x & 63;
    if (wid >= BATCH) return;
    const int* hd = (const int*)act3 + (size_t)wid * 256;
    const int* wd = (const int*)swf2;
    int acc[10];
#pragma unroll
    for (int o = 0; o < 10; o++) acc[o] = 0;
#pragma unroll
    for (int i = 0; i < 4; i++) {
        int k4 = i * 64 + lane;
        int hv = hd[k4];
#pragma unroll
        for (int o = 0; o < 10; o++)
            acc[o] = sdot4(hv, wd[o * 256 + k4], acc[o]);
    }
#pragma unroll
    for (int o = 0; o < 10; o++)
#pragma unroll
        for (int s = 32; s > 0; s >>= 1) acc[o] += __shfl_xor(acc[o], s);
    if (lane == 0) {
        float logit[10];
        float mx = -1e30f;
#pragma unroll
        for (int o = 0; o < 10; o++) {
            float z = (float)acc[o] + bf2[o];
            float bn = (z - mf2[o]) * (gf2[o] / sqrtf(vf2[o] + 1e-5f)) + bef2[o];
            logit[o] = bn;
            mx = fmaxf(mx, bn);
        }
        float s = 0.f;
#pragma unroll
        for (int o = 0; o < 10; o++) s += expf(logit[o] - mx);
        float lse = mx + logf(s);
#pragma unroll
        for (int o = 0; o < 10; o++) out[(size_t)wid * 10 + o] = logit[o] - lse;
    }
}

extern "C" void kernel_launch(void* const* d_in, const int* in_sizes, int n_in,
                              void* d_out, int out_size, void* d_ws, size_t ws_size,
                              hipStream_t stream) {
    const float* x   = (const float*)d_in[0];
    const float* w1  = (const float*)d_in[1];
    const float* b1  = (const float*)d_in[2];
    const float* g1  = (const float*)d_in[3];
    const float* be1 = (const float*)d_in[4];
    const float* m1  = (const float*)d_in[5];
    const float* v1  = (const float*)d_in[6];
    const float* w2  = (const float*)d_in[7];
    const float* b2  = (const float*)d_in[8];
    const float* g2  = (const float*)d_in[9];
    const float* be2 = (const float*)d_in[10];
    const float* m2  = (const float*)d_in[11];
    const float* v2  = (const float*)d_in[12];
    const float* wf1 = (const float*)d_in[13];
    const float* bf1 = (const float*)d_in[14];
    const float* gf1 = (const float*)d_in[15];
    const float* bef1= (const float*)d_in[16];
    const float* mf1 = (const float*)d_in[17];
    const float* vf1 = (const float*)d_in[18];
    const float* wf2 = (const float*)d_in[19];
    const float* bf2 = (const float*)d_in[20];
    const float* gf2 = (const float*)d_in[21];
    const float* bef2= (const float*)d_in[22];
    const float* mf2 = (const float*)d_in[23];
    const float* vf2 = (const float*)d_in[24];
    float* out = (float*)d_out;

    // ws layout (all int8)
    char* ws = (char*)d_ws;
    signed char* act1 = (signed char*)ws;                  // 2048*9248     = 18,939,904
    signed char* act2 = act1 + 18939904;                   // 2048*2304     =  4,718,592
    signed char* act3 = act2 + 4718592;                    // 2048*1024     =  2,097,152
    signed char* w2p  = act3 + 2097152;                    // 25*2*64*16    =     51,200
    signed char* wf1s = w2p + 51200;                       // 1024*2304     =  2,359,296
    signed char* wf2p = wf1s + 2359296;                    // 10*1024       =     10,240

    k1_prep<<<1024, 512, 0, stream>>>(x, w1, b1, g1, be1, m1, v1, w2, wf1, wf2,
                                      w2p, wf1s, wf2p, act1);

    k2_mfma<<<256, 768, 0, stream>>>(act1, w2p, b2, g2, be2, m2, v2, act2);

    k3_mfma<<<256, 256, 0, stream>>>(act2, wf1s, bf1, gf1, bef1, mf1, vf1, act3);

    k4_fc2<<<512, 256, 0, stream>>>(act3, wf2p, bf2, gf2, bef2, mf2, vf2, out);
}

// Round 31
// 60.123 us; speedup vs baseline: 1.0551x; 1.0065x over previous
//
#include <hip/hip_runtime.h>
#include <math.h>

#define BATCH 2048

typedef __attribute__((ext_vector_type(4))) int i32x4;
typedef __attribute__((ext_vector_type(16))) int i32x16;
typedef __attribute__((ext_vector_type(2))) float f32x2;

__device__ __forceinline__ int sdot4(int a, int b, int c) {
    return __builtin_amdgcn_sdot4(a, b, c, false);
}

__device__ __forceinline__ float fsign(float v) {
    return v > 0.f ? 1.f : (v < 0.f ? -1.f : 0.f);
}

// act swizzle (T2): flips addr bits 4-6 by pixel bits 2-4; bijective on [0,9248),
// keeps 16B chunks intact, independent of the low 5 bits (oc).
__device__ __forceinline__ int aswz(int off) {
    return off ^ (((off >> 7) & 7) << 4);
}

// K1 + prep fused. 2 images/block, 512 threads. Conv: px-PAIR sliding window
// (A/B/C f32x2 file): px=2p from {A,pm1,B}, px=2p+1 from {B,pm2,C}; rotation
// A<-C, B reloaded UNCONDITIONALLY (cols 4p+6,4p+7 <= 26,27 in-bounds) so the
// trailing px=12 window sees B = cols 26,27. Bit-identical chains vs r29.
__global__ __launch_bounds__(512) void k1_prep(
        const float* __restrict__ x,
        const float* __restrict__ w1, const float* __restrict__ b1,
        const float* __restrict__ g1, const float* __restrict__ be1,
        const float* __restrict__ m1, const float* __restrict__ v1,
        const float* __restrict__ w2, const float* __restrict__ wf1,
        const float* __restrict__ wf2,
        signed char* __restrict__ w2p, signed char* __restrict__ wf1s,
        signed char* __restrict__ wf2p, signed char* __restrict__ act1) {
    __shared__ __align__(16) float xs[1568];           // 2 images
    __shared__ __align__(16) signed char lact[10816];  // 2 x [169][32]
    int blk = blockIdx.x, tid = threadIdx.x;
    int b0 = blk * 2;

    // stage 2 images (coalesced float4)
    if (tid < 392) ((float4*)xs)[tid] = ((const float4*)(x + (size_t)b0 * 784))[tid];

    // ---- prep slice: 2364 elements (1024 blocks x 2364 = 2,420,736) ----
    {
        int base = blk * 2364;
        for (int t = tid; t < 2364; t += 512) {
            int i = base + t;
            if (i < 2359296) {                  // wf1 sign (natural layout)
                float v = wf1[i];
                wf1s[i] = v > 0.f ? 1 : (v < 0.f ? -1 : 0);
            } else if (i < 2359296 + 51200) {   // w2p [tap][half][oc][16]
                int ii = i - 2359296;
                int tap = ii >> 11;
                int r = ii & 2047;
                int half = r >> 10;
                int r2 = r & 1023;
                int oc = r2 >> 4, j = r2 & 15;
                int ic = half * 16 + j;
                float v = w2[(oc * 32 + ic) * 25 + tap];
                w2p[ii] = v > 0.f ? 1 : (v < 0.f ? -1 : 0);
            } else {                            // wf2 sign
                int ii = i - 2359296 - 51200;
                float v = wf2[ii];
                wf2p[ii] = v > 0.f ? 1 : (v < 0.f ? -1 : 0);
            }
        }
    }

    // zero the border pixels of both images (480 x 16B chunks)
    i32x4 z4 = {0, 0, 0, 0};
    if (tid < 480) {
        int img = tid / 240, ii = tid - img * 240;
        int pi = ii >> 1, half = ii & 1;
        int p;
        if (pi < 34) p = pi;                       // rows 0-1
        else if (pi < 68) p = 255 + (pi - 34);     // rows 15-16
        else {                                     // rows 2-14, cols 0,1,15,16
            int j2 = pi - 68;
            int row = 2 + (j2 >> 2), c = j2 & 3;
            int col = (c < 2) ? c : 13 + c;        // 0,1,15,16
            p = row * 17 + col;
        }
        *(i32x4*)(act1 + (size_t)(b0 + img) * 9248 + aswz(p * 32 + half * 16)) = z4;
    }
    __syncthreads();   // xs ready

    // ---- conv1 + BN + sign + pool2 (px-pair sliding window, pk-FMA) ----
    {
        int oc = tid & 31, slot = tid >> 5;   // 16 slots
        float sw[9];
#pragma unroll
        for (int i = 0; i < 9; i++) sw[i] = fsign(w1[oc * 9 + i]);
        float bias = b1[oc], m = m1[oc];
        float sc = g1[oc] / sqrtf(v1[oc] + 1e-5f), bb = be1[oc];
#pragma unroll
        for (int it = 0; it < 2; ++it) {
            int r = slot + 16 * it;           // 0..25 = 2 img x 13 py
            if (r < 26) {
                int img = (r >= 13) ? 1 : 0;
                int py = r - img * 13;
                const float* rowp = xs + img * 784 + py * 56;   // conv row 2py
                signed char* lrow = lact + img * 5408 + py * 416 + oc;

                f32x2 A[4], B[4], C[4];
#pragma unroll
                for (int dy = 0; dy < 4; dy++) {
                    A[dy] = *(const f32x2*)(rowp + dy * 28);      // cols 0,1
                    B[dy] = *(const f32x2*)(rowp + dy * 28 + 2);  // cols 2,3
                }
#pragma unroll
                for (int p = 0; p < 6; p++) {      // px = 2p, 2p+1
#pragma unroll
                    for (int dy = 0; dy < 4; dy++)
                        C[dy] = *(const f32x2*)(rowp + dy * 28 + 4 * p + 4);
                    f32x2 pm1[4], pm2[4];
#pragma unroll
                    for (int dy = 0; dy < 4; dy++) {
                        pm1[dy].x = A[dy].y; pm1[dy].y = B[dy].x;
                        pm2[dy].x = B[dy].y; pm2[dy].y = C[dy].x;
                    }
                    f32x2 a01 = {0.f, 0.f}, a23 = {0.f, 0.f};
                    f32x2 b01 = {0.f, 0.f}, b23 = {0.f, 0.f};
#pragma unroll
                    for (int ky = 0; ky < 3; ky++) {
                        a01 += A[ky] * sw[ky * 3 + 0];
                        a01 += pm1[ky] * sw[ky * 3 + 1];
                        a01 += B[ky] * sw[ky * 3 + 2];
                        a23 += A[ky + 1] * sw[ky * 3 + 0];
                        a23 += pm1[ky + 1] * sw[ky * 3 + 1];
                        a23 += B[ky + 1] * sw[ky * 3 + 2];
                        b01 += B[ky] * sw[ky * 3 + 0];
                        b01 += pm2[ky] * sw[ky * 3 + 1];
                        b01 += C[ky] * sw[ky * 3 + 2];
                        b23 += B[ky + 1] * sw[ky * 3 + 0];
                        b23 += pm2[ky + 1] * sw[ky * 3 + 1];
                        b23 += C[ky + 1] * sw[ky * 3 + 2];
                    }
                    float mA = fmaxf(fmaxf(a01.x, a01.y), fmaxf(a23.x, a23.y));
                    float mB = fmaxf(fmaxf(b01.x, b01.y), fmaxf(b23.x, b23.y));
                    float bnA = (mA + bias - m) * sc + bb;   // same assoc as r29
                    float bnB = (mB + bias - m) * sc + bb;
                    lrow[(2 * p) * 32] = (signed char)fsign(bnA);
                    lrow[(2 * p + 1) * 32] = (signed char)fsign(bnB);
#pragma unroll
                    for (int dy = 0; dy < 4; dy++) {
                        A[dy] = C[dy];                         // rotate
                        B[dy] = *(const f32x2*)(rowp + dy * 28 + 4 * p + 6);
                    }   // max offset 4*5+6 = 26 -> cols 26,27: in-bounds
                }
                // trailing px = 12: window cols 24..27 = A(24,25), B(26,27)
                {
                    f32x2 pm1[4];
#pragma unroll
                    for (int dy = 0; dy < 4; dy++) {
                        pm1[dy].x = A[dy].y; pm1[dy].y = B[dy].x;
                    }
                    f32x2 a01 = {0.f, 0.f}, a23 = {0.f, 0.f};
#pragma unroll
                    for (int ky = 0; ky < 3; ky++) {
                        a01 += A[ky] * sw[ky * 3 + 0];
                        a01 += pm1[ky] * sw[ky * 3 + 1];
                        a01 += B[ky] * sw[ky * 3 + 2];
                        a23 += A[ky + 1] * sw[ky * 3 + 0];
                        a23 += pm1[ky + 1] * sw[ky * 3 + 1];
                        a23 += B[ky + 1] * sw[ky * 3 + 2];
                    }
                    float mA = fmaxf(fmaxf(a01.x, a01.y), fmaxf(a23.x, a23.y));
                    float bnA = (mA + bias - m) * sc + bb;
                    lrow[12 * 32] = (signed char)fsign(bnA);
                }
            }
        }
    }
    __syncthreads();

    // ---- copy-out: pad+aswz mapping, coalesced 16B global writes ----
    for (int i = tid; i < 676; i += 512) {
        int img = i / 338, rr = i - img * 338;
        int pix = rr >> 1, half = rr & 1;
        int py2 = pix / 13, px2 = pix - py2 * 13;
        int p = (py2 + 2) * 17 + (px2 + 2);
        *(i32x4*)(act1 + (size_t)(b0 + img) * 9248 + aswz(p * 32 + half * 16)) =
            *(const i32x4*)(lact + img * 5408 + pix * 32 + half * 16);
    }
}

// K2: conv2 implicit-GEMM MFMA i8. Block = 8 images, 12 waves (768 thr).
// Grid = 256 = 1 block/CU. Staging = pure linear copy. (r29 verbatim)
#define K2_IMG_STRIDE 9248          // 17*17*32
#define K2_WOFF 73984               // 8*9248
__global__ __launch_bounds__(768) void k2_mfma(
        const signed char* __restrict__ act1, const signed char* __restrict__ w2p,
        const float* __restrict__ b2, const float* __restrict__ g2,
        const float* __restrict__ be2, const float* __restrict__ m2,
        const float* __restrict__ v2, signed char* __restrict__ act2) {
    __shared__ __align__(16) signed char smem[125184];
    int tid = threadIdx.x;
    int b0 = blockIdx.x * 8;

    {
        const i32x4* asrc = (const i32x4*)(act1 + (size_t)b0 * 9248);
        i32x4* s4 = (i32x4*)smem;
        for (int i = tid; i < 4624; i += 768) s4[i] = asrc[i];
        const i32x4* wsrc = (const i32x4*)w2p;
        i32x4* w4 = (i32x4*)(smem + K2_WOFF);
        for (int i = tid; i < 3200; i += 768) w4[i] = wsrc[i];
    }
    __syncthreads();

    int wave = tid >> 6, lane = tid & 63;
    int lrow = lane & 31, kh = lane >> 5;
    const signed char* wbase = smem + K2_WOFF + kh * 1024 + lrow * 16;

    const signed char* aimg[3];
    int pixbase[3];
#pragma unroll
    for (int t = 0; t < 3; ++t) {
        int mt = wave * 3 + t;                // 0..35
        int m = mt * 32 + lrow;
        int q = m >> 2, j = m & 3;
        int img = q / 36, qq = q - img * 36;
        int oy = 2 * (qq / 6) + (j >> 1);
        int ox = 2 * (qq - (qq / 6) * 6) + (j & 1);
        aimg[t] = smem + img * K2_IMG_STRIDE;
        pixbase[t] = oy * 17 + ox;
    }

    i32x16 acc[3][2] = {};
#pragma unroll 5
    for (int tap = 0; tap < 25; ++tap) {
        int ky = tap / 5, kx = tap - (tap / 5) * 5;
        i32x4 w0 = *(const i32x4*)(wbase + tap * 2048);        // oc = lrow
        i32x4 w1v = *(const i32x4*)(wbase + tap * 2048 + 512); // oc = 32+lrow
#pragma unroll
        for (int t = 0; t < 3; ++t) {
            int off = (pixbase[t] + ky * 17 + kx) * 32 + kh * 16;
            i32x4 a = *(const i32x4*)(aimg[t] + aswz(off));
            acc[t][0] = __builtin_amdgcn_mfma_i32_32x32x32_i8(a, w0, acc[t][0], 0, 0, 0);
            acc[t][1] = __builtin_amdgcn_mfma_i32_32x32x32_i8(a, w1v, acc[t][1], 0, 0, 0);
        }
    }
    __syncthreads();   // all LDS A/W reads done -> act region reusable

    float bi[2], mm2[2], sc2[2], bb2[2];
#pragma unroll
    for (int h = 0; h < 2; ++h) {
        int oc = h * 32 + lrow;
        bi[h] = b2[oc]; mm2[h] = m2[oc];
        sc2[h] = g2[oc] / sqrtf(v2[oc] + 1e-5f); bb2[h] = be2[oc];
    }
#pragma unroll
    for (int t = 0; t < 3; ++t) {
        int mt = wave * 3 + t;
#pragma unroll
        for (int h = 0; h < 2; ++h) {
            int oc = h * 32 + lrow;
#pragma unroll
            for (int g = 0; g < 4; g++) {
                int qo = mt * 8 + kh + 2 * g;     // pool cell 0..287 (8 images)
                int imo = qo / 36, qqo = qo - imo * 36;
                float best = -2.f;
#pragma unroll
                for (int jj = 0; jj < 4; jj++) {
                    float z = (float)acc[t][h][g * 4 + jj] + bi[h];
                    float bn = (z - mm2[h]) * sc2[h] + bb2[h];
                    best = fmaxf(best, fsign(bn));
                }
                smem[imo * 2304 + oc * 36 + qqo] = (signed char)best;
            }
        }
    }
    __syncthreads();
    {
        const i32x4* s4o = (const i32x4*)smem;
        i32x4* dst = (i32x4*)(act2 + (size_t)b0 * 2304);
        for (int i = tid; i < 1152; i += 768) dst[i] = s4o[i];
    }
}

// K3: fc1 as LDS-tiled MFMA i8 GEMM 2048x1024x2304. (r29 verbatim)
#define K3A_SEG 2064                // 128*16 + 16 pad
#define K3B_SEG 1040                // 64*16 + 16 pad
#define K3_BOFF 16512               // 8 * 2064
__global__ __launch_bounds__(256) void k3_mfma(
        const signed char* __restrict__ act2, const signed char* __restrict__ wf1s,
        const float* __restrict__ bf1, const float* __restrict__ gf1,
        const float* __restrict__ bef1, const float* __restrict__ mf1,
        const float* __restrict__ vf1, signed char* __restrict__ act3) {
    __shared__ __align__(16) signed char s[K3_BOFF + 8 * K3B_SEG];  // 24832
    int tid = threadIdx.x;
    int bid = blockIdx.x;
    int tn = bid & 15, tm = bid >> 4;

    const signed char* Ab = act2 + (size_t)tm * 128 * 2304;
    const signed char* Bb = wf1s + (size_t)tn * 64 * 2304;
    size_t gA[4]; int lwA[4];
#pragma unroll
    for (int i = 0; i < 4; i++) {
        int e = tid + 256 * i, row = e >> 3, sg = (e + row) & 7;
        gA[i] = (size_t)row * 2304 + sg * 16;
        lwA[i] = sg * K3A_SEG + row * 16;
    }
    size_t gB[2]; int lwB[2];
#pragma unroll
    for (int i = 0; i < 2; i++) {
        int e = tid + 256 * i, row = e >> 3, sg = (e + row) & 7;
        gB[i] = (size_t)row * 2304 + sg * 16;
        lwB[i] = K3_BOFF + sg * K3B_SEG + row * 16;
    }

    i32x4 ra[4], rb[2];
#pragma unroll
    for (int i = 0; i < 4; i++) ra[i] = *(const i32x4*)(Ab + gA[i]);
#pragma unroll
    for (int i = 0; i < 2; i++) rb[i] = *(const i32x4*)(Bb + gB[i]);

    int l = tid & 63, wid = tid >> 6;
    int lrow = l & 31, kh = l >> 5;
    int raddrA = kh * K3A_SEG + (wid * 32 + lrow) * 16;
    int raddrB0 = K3_BOFF + kh * K3B_SEG + lrow * 16;
    int raddrB1 = raddrB0 + 32 * 16;

    i32x16 acc0 = {0};
    i32x16 acc1 = {0};
    for (int t = 0; t < 18; ++t) {
        if (t) __syncthreads();
#pragma unroll
        for (int i = 0; i < 4; i++) *(i32x4*)(s + lwA[i]) = ra[i];
#pragma unroll
        for (int i = 0; i < 2; i++) *(i32x4*)(s + lwB[i]) = rb[i];
        if (t < 17) {
            size_t ko = (size_t)(t + 1) * 128;
#pragma unroll
            for (int i = 0; i < 4; i++) ra[i] = *(const i32x4*)(Ab + gA[i] + ko);
#pragma unroll
            for (int i = 0; i < 2; i++) rb[i] = *(const i32x4*)(Bb + gB[i] + ko);
        }
        __syncthreads();
#pragma unroll
        for (int ks = 0; ks < 4; ++ks) {
            i32x4 a  = *(const i32x4*)(s + raddrA + ks * 2 * K3A_SEG);
            i32x4 b0 = *(const i32x4*)(s + raddrB0 + ks * 2 * K3B_SEG);
            i32x4 b1 = *(const i32x4*)(s + raddrB1 + ks * 2 * K3B_SEG);
            acc0 = __builtin_amdgcn_mfma_i32_32x32x32_i8(a, b0, acc0, 0, 0, 0);
            acc1 = __builtin_amdgcn_mfma_i32_32x32x32_i8(a, b1, acc1, 0, 0, 0);
        }
    }

    int col0 = tn * 64 + lrow;
    int col1 = col0 + 32;
    float bi0 = bf1[col0], m0 = mf1[col0];
    float sc0 = gf1[col0] / sqrtf(vf1[col0] + 1e-5f), bb0 = bef1[col0];
    float bi1 = bf1[col1], m1 = mf1[col1];
    float sc1 = gf1[col1] / sqrtf(vf1[col1] + 1e-5f), bb1 = bef1[col1];
    __syncthreads();   // K-loop reads of s done -> reuse as output tile [128][64]
#pragma unroll
    for (int r = 0; r < 16; r++) {
        int rowl = wid * 32 + (r & 3) + 8 * (r >> 2) + 4 * kh;
        float bn0 = ((float)acc0[r] + bi0 - m0) * sc0 + bb0;
        float bn1 = ((float)acc1[r] + bi1 - m1) * sc1 + bb1;
        s[rowl * 64 + lrow] = (signed char)fsign(bn0);
        s[rowl * 64 + lrow + 32] = (signed char)fsign(bn1);
    }
    __syncthreads();
    for (int i = tid; i < 512; i += 256) {
        int rl = i >> 2, c16 = i & 3;
        *(i32x4*)(act3 + (size_t)(tm * 128 + rl) * 1024 + tn * 64 + c16 * 16) =
            *(const i32x4*)(s + i * 16);
    }
}

// K4: fc2 (1024->10) + bias + BN + log_softmax. One wave per image. (unchanged)
__global__ void k4_fc2(const signed char* __restrict__ act3, const signed char* __restrict__ swf2,
                       const float* __restrict__ bf2, const float* __restrict__ gf2,
                       const float* __restrict__ bef2, const float* __restrict__ mf2,
                       const float* __restrict__ vf2, float* __restrict__ out) {
    int wid = (blockIdx.x * 256 + threadIdx.x) >> 6;
    int lane = threadIdx.x & 63;
    if (wid >= BATCH) return;
    const int* hd = (const int*)act3 + (size_t)wid * 256;
    const int* wd = (const int*)swf2;
    int acc[10];
#pragma unroll
    for (int o = 0; o < 10; o++) acc[o] = 0;
#pragma unroll
    for (int i = 0; i < 4; i++) {
        int k4 = i * 64 + lane;
        int hv = hd[k4];
#pragma unroll
        for (int o = 0; o < 10; o++)
            acc[o] = sdot4(hv, wd[o * 256 + k4], acc[o]);
    }
#pragma unroll
    for (int o = 0; o < 10; o++)
#pragma unroll
        for (int s = 32; s > 0; s >>= 1) acc[o] += __shfl_xor(acc[o], s);
    if (lane == 0) {
        float logit[10];
        float mx = -1e30f;
#pragma unroll
        for (int o = 0; o < 10; o++) {
            float z = (float)acc[o] + bf2[o];
            float bn = (z - mf2[o]) * (gf2[o] / sqrtf(vf2[o] + 1e-5f)) + bef2[o];
            logit[o] = bn;
            mx = fmaxf(mx, bn);
        }
        float s = 0.f;
#pragma unroll
        for (int o = 0; o < 10; o++) s += expf(logit[o] - mx);
        float lse = mx + logf(s);
#pragma unroll
        for (int o = 0; o < 10; o++) out[(size_t)wid * 10 + o] = logit[o] - lse;
    }
}

extern "C" void kernel_launch(void* const* d_in, const int* in_sizes, int n_in,
                              void* d_out, int out_size, void* d_ws, size_t ws_size,
                              hipStream_t stream) {
    const float* x   = (const float*)d_in[0];
    const float* w1  = (const float*)d_in[1];
    const float* b1  = (const float*)d_in[2];
    const float* g1  = (const float*)d_in[3];
    const float* be1 = (const float*)d_in[4];
    const float* m1  = (const float*)d_in[5];
    const float* v1  = (const float*)d_in[6];
    const float* w2  = (const float*)d_in[7];
    const float* b2  = (const float*)d_in[8];
    const float* g2  = (const float*)d_in[9];
    const float* be2 = (const float*)d_in[10];
    const float* m2  = (const float*)d_in[11];
    const float* v2  = (const float*)d_in[12];
    const float* wf1 = (const float*)d_in[13];
    const float* bf1 = (const float*)d_in[14];
    const float* gf1 = (const float*)d_in[15];
    const float* bef1= (const float*)d_in[16];
    const float* mf1 = (const float*)d_in[17];
    const float* vf1 = (const float*)d_in[18];
    const float* wf2 = (const float*)d_in[19];
    const float* bf2 = (const float*)d_in[20];
    const float* gf2 = (const float*)d_in[21];
    const float* bef2= (const float*)d_in[22];
    const float* mf2 = (const float*)d_in[23];
    const float* vf2 = (const float*)d_in[24];
    float* out = (float*)d_out;

    // ws layout (all int8)
    char* ws = (char*)d_ws;
    signed char* act1 = (signed char*)ws;                  // 2048*9248     = 18,939,904
    signed char* act2 = act1 + 18939904;                   // 2048*2304     =  4,718,592
    signed char* act3 = act2 + 4718592;                    // 2048*1024     =  2,097,152
    signed char* w2p  = act3 + 2097152;                    // 25*2*64*16    =     51,200
    signed char* wf1s = w2p + 51200;                       // 1024*2304     =  2,359,296
    signed char* wf2p = wf1s + 2359296;                    // 10*1024       =     10,240

    k1_prep<<<1024, 512, 0, stream>>>(x, w1, b1, g1, be1, m1, v1, w2, wf1, wf2,
                                      w2p, wf1s, wf2p, act1);

    k2_mfma<<<256, 768, 0, stream>>>(act1, w2p, b2, g2, be2, m2, v2, act2);

    k3_mfma<<<256, 256, 0, stream>>>(act2, wf1s, bf1, gf1, bef1, mf1, vf1, act3);

    k4_fc2<<<512, 256, 0, stream>>>(act3, wf2p, bf2, gf2, bef2, mf2, vf2, out);
}

// Round 32
// 59.099 us; speedup vs baseline: 1.0734x; 1.0173x over previous
//
#include <hip/hip_runtime.h>
#include <math.h>

#define BATCH 2048

typedef __attribute__((ext_vector_type(4))) int i32x4;
typedef __attribute__((ext_vector_type(16))) int i32x16;
typedef __attribute__((ext_vector_type(2))) float f32x2;

__device__ __forceinline__ int sdot4(int a, int b, int c) {
    return __builtin_amdgcn_sdot4(a, b, c, false);
}

__device__ __forceinline__ float fsign(float v) {
    return v > 0.f ? 1.f : (v < 0.f ? -1.f : 0.f);
}

// act swizzle (T2): flips addr bits 4-6 by pixel bits 2-4; bijective on [0,9248),
// keeps 16B chunks intact, independent of the low 5 bits (oc).
__device__ __forceinline__ int aswz(int off) {
    return off ^ (((off >> 7) & 7) << 4);
}

// K1 + prep fused. 2 images/block, 512 threads. Conv: px-pair sliding window
// (r31 verbatim, bit-identical). act1 is now COMPACT [b][169][32] (5408 B/img):
// copy-out is a pure linear coalesced copy; border/pad work moved to k2's LDS.
__global__ __launch_bounds__(512) void k1_prep(
        const float* __restrict__ x,
        const float* __restrict__ w1, const float* __restrict__ b1,
        const float* __restrict__ g1, const float* __restrict__ be1,
        const float* __restrict__ m1, const float* __restrict__ v1,
        const float* __restrict__ w2, const float* __restrict__ wf1,
        const float* __restrict__ wf2,
        signed char* __restrict__ w2p, signed char* __restrict__ wf1s,
        signed char* __restrict__ wf2p, signed char* __restrict__ act1) {
    __shared__ __align__(16) float xs[1568];           // 2 images
    __shared__ __align__(16) signed char lact[10816];  // 2 x [169][32]
    int blk = blockIdx.x, tid = threadIdx.x;
    int b0 = blk * 2;

    // stage 2 images (coalesced float4)
    if (tid < 392) ((float4*)xs)[tid] = ((const float4*)(x + (size_t)b0 * 784))[tid];

    // ---- prep slice: 2364 elements (1024 blocks x 2364 = 2,420,736) ----
    {
        int base = blk * 2364;
        for (int t = tid; t < 2364; t += 512) {
            int i = base + t;
            if (i < 2359296) {                  // wf1 sign (natural layout)
                float v = wf1[i];
                wf1s[i] = v > 0.f ? 1 : (v < 0.f ? -1 : 0);
            } else if (i < 2359296 + 51200) {   // w2p [tap][half][oc][16]
                int ii = i - 2359296;
                int tap = ii >> 11;
                int r = ii & 2047;
                int half = r >> 10;
                int r2 = r & 1023;
                int oc = r2 >> 4, j = r2 & 15;
                int ic = half * 16 + j;
                float v = w2[(oc * 32 + ic) * 25 + tap];
                w2p[ii] = v > 0.f ? 1 : (v < 0.f ? -1 : 0);
            } else {                            // wf2 sign
                int ii = i - 2359296 - 51200;
                float v = wf2[ii];
                wf2p[ii] = v > 0.f ? 1 : (v < 0.f ? -1 : 0);
            }
        }
    }
    __syncthreads();   // xs ready

    // ---- conv1 + BN + sign + pool2 (px-pair sliding window, pk-FMA) ----
    {
        int oc = tid & 31, slot = tid >> 5;   // 16 slots
        float sw[9];
#pragma unroll
        for (int i = 0; i < 9; i++) sw[i] = fsign(w1[oc * 9 + i]);
        float bias = b1[oc], m = m1[oc];
        float sc = g1[oc] / sqrtf(v1[oc] + 1e-5f), bb = be1[oc];
#pragma unroll
        for (int it = 0; it < 2; ++it) {
            int r = slot + 16 * it;           // 0..25 = 2 img x 13 py
            if (r < 26) {
                int img = (r >= 13) ? 1 : 0;
                int py = r - img * 13;
                const float* rowp = xs + img * 784 + py * 56;   // conv row 2py
                signed char* lrow = lact + img * 5408 + py * 416 + oc;

                f32x2 A[4], B[4], C[4];
#pragma unroll
                for (int dy = 0; dy < 4; dy++) {
                    A[dy] = *(const f32x2*)(rowp + dy * 28);      // cols 0,1
                    B[dy] = *(const f32x2*)(rowp + dy * 28 + 2);  // cols 2,3
                }
#pragma unroll
                for (int p = 0; p < 6; p++) {      // px = 2p, 2p+1
#pragma unroll
                    for (int dy = 0; dy < 4; dy++)
                        C[dy] = *(const f32x2*)(rowp + dy * 28 + 4 * p + 4);
                    f32x2 pm1[4], pm2[4];
#pragma unroll
                    for (int dy = 0; dy < 4; dy++) {
                        pm1[dy].x = A[dy].y; pm1[dy].y = B[dy].x;
                        pm2[dy].x = B[dy].y; pm2[dy].y = C[dy].x;
                    }
                    f32x2 a01 = {0.f, 0.f}, a23 = {0.f, 0.f};
                    f32x2 b01 = {0.f, 0.f}, b23 = {0.f, 0.f};
#pragma unroll
                    for (int ky = 0; ky < 3; ky++) {
                        a01 += A[ky] * sw[ky * 3 + 0];
                        a01 += pm1[ky] * sw[ky * 3 + 1];
                        a01 += B[ky] * sw[ky * 3 + 2];
                        a23 += A[ky + 1] * sw[ky * 3 + 0];
                        a23 += pm1[ky + 1] * sw[ky * 3 + 1];
                        a23 += B[ky + 1] * sw[ky * 3 + 2];
                        b01 += B[ky] * sw[ky * 3 + 0];
                        b01 += pm2[ky] * sw[ky * 3 + 1];
                        b01 += C[ky] * sw[ky * 3 + 2];
                        b23 += B[ky + 1] * sw[ky * 3 + 0];
                        b23 += pm2[ky + 1] * sw[ky * 3 + 1];
                        b23 += C[ky + 1] * sw[ky * 3 + 2];
                    }
                    float mA = fmaxf(fmaxf(a01.x, a01.y), fmaxf(a23.x, a23.y));
                    float mB = fmaxf(fmaxf(b01.x, b01.y), fmaxf(b23.x, b23.y));
                    float bnA = (mA + bias - m) * sc + bb;   // same assoc as r31
                    float bnB = (mB + bias - m) * sc + bb;
                    lrow[(2 * p) * 32] = (signed char)fsign(bnA);
                    lrow[(2 * p + 1) * 32] = (signed char)fsign(bnB);
#pragma unroll
                    for (int dy = 0; dy < 4; dy++) {
                        A[dy] = C[dy];                         // rotate
                        B[dy] = *(const f32x2*)(rowp + dy * 28 + 4 * p + 6);
                    }   // max offset 4*5+6 = 26 -> cols 26,27: in-bounds
                }
                // trailing px = 12: window cols 24..27 = A(24,25), B(26,27)
                {
                    f32x2 pm1[4];
#pragma unroll
                    for (int dy = 0; dy < 4; dy++) {
                        pm1[dy].x = A[dy].y; pm1[dy].y = B[dy].x;
                    }
                    f32x2 a01 = {0.f, 0.f}, a23 = {0.f, 0.f};
#pragma unroll
                    for (int ky = 0; ky < 3; ky++) {
                        a01 += A[ky] * sw[ky * 3 + 0];
                        a01 += pm1[ky] * sw[ky * 3 + 1];
                        a01 += B[ky] * sw[ky * 3 + 2];
                        a23 += A[ky + 1] * sw[ky * 3 + 0];
                        a23 += pm1[ky + 1] * sw[ky * 3 + 1];
                        a23 += B[ky + 1] * sw[ky * 3 + 2];
                    }
                    float mA = fmaxf(fmaxf(a01.x, a01.y), fmaxf(a23.x, a23.y));
                    float bnA = (mA + bias - m) * sc + bb;
                    lrow[12 * 32] = (signed char)fsign(bnA);
                }
            }
        }
    }
    __syncthreads();

    // ---- copy-out: PURE LINEAR (compact act1 = lact layout), coalesced ----
    {
        const i32x4* src = (const i32x4*)lact;
        i32x4* dst = (i32x4*)(act1 + (size_t)b0 * 5408);
        for (int i = tid; i < 676; i += 512) dst[i] = src[i];
    }
}

// K2: conv2 implicit-GEMM MFMA i8. Block = 8 images, 12 waves (768 thr).
// Grid = 256 = 1 block/CU. Staging now reads COMPACT act1 (11 MB total) and
// reconstructs pad+aswz in LDS (scatter writes); borders zeroed in LDS
// (disjoint addresses, no extra barrier). MFMA core r31 verbatim.
#define K2_IMG_STRIDE 9248          // 17*17*32
#define K2_WOFF 73984               // 8*9248
__global__ __launch_bounds__(768) void k2_mfma(
        const signed char* __restrict__ act1, const signed char* __restrict__ w2p,
        const float* __restrict__ b2, const float* __restrict__ g2,
        const float* __restrict__ be2, const float* __restrict__ m2,
        const float* __restrict__ v2, signed char* __restrict__ act2) {
    __shared__ __align__(16) signed char smem[125184];
    int tid = threadIdx.x;
    int b0 = blockIdx.x * 8;

    {
        // weights (linear)
        const i32x4* wsrc = (const i32x4*)w2p;
        i32x4* w4 = (i32x4*)(smem + K2_WOFF);
        for (int i = tid; i < 3200; i += 768) w4[i] = wsrc[i];
        // act interior: compact global (coalesced reads) -> padded+swizzled LDS
        const i32x4* asrc = (const i32x4*)(act1 + (size_t)b0 * 5408);
        for (int i = tid; i < 2704; i += 768) {       // 8 img x 338 chunks
            int img = i / 338, rr = i - img * 338;
            int pix = rr >> 1, half = rr & 1;
            int py = pix / 13, px = pix - py * 13;
            int p = (py + 2) * 17 + (px + 2);
            *(i32x4*)(smem + img * K2_IMG_STRIDE + aswz(p * 32 + half * 16)) = asrc[i];
        }
        // borders: zero (8 img x 240 chunks; disjoint from interior)
        i32x4 z4 = {0, 0, 0, 0};
        for (int i = tid; i < 1920; i += 768) {
            int img = i / 240, ii = i - img * 240;
            int pi = ii >> 1, half = ii & 1;
            int p;
            if (pi < 34) p = pi;                       // rows 0-1
            else if (pi < 68) p = 255 + (pi - 34);     // rows 15-16
            else {                                     // rows 2-14, cols 0,1,15,16
                int j2 = pi - 68;
                int row = 2 + (j2 >> 2), c = j2 & 3;
                int col = (c < 2) ? c : 13 + c;        // 0,1,15,16
                p = row * 17 + col;
            }
            *(i32x4*)(smem + img * K2_IMG_STRIDE + aswz(p * 32 + half * 16)) = z4;
        }
    }
    __syncthreads();

    int wave = tid >> 6, lane = tid & 63;
    int lrow = lane & 31, kh = lane >> 5;
    const signed char* wbase = smem + K2_WOFF + kh * 1024 + lrow * 16;

    const signed char* aimg[3];
    int pixbase[3];
#pragma unroll
    for (int t = 0; t < 3; ++t) {
        int mt = wave * 3 + t;                // 0..35
        int m = mt * 32 + lrow;
        int q = m >> 2, j = m & 3;
        int img = q / 36, qq = q - img * 36;
        int oy = 2 * (qq / 6) + (j >> 1);
        int ox = 2 * (qq - (qq / 6) * 6) + (j & 1);
        aimg[t] = smem + img * K2_IMG_STRIDE;
        pixbase[t] = oy * 17 + ox;
    }

    i32x16 acc[3][2] = {};
#pragma unroll 5
    for (int tap = 0; tap < 25; ++tap) {
        int ky = tap / 5, kx = tap - (tap / 5) * 5;
        i32x4 w0 = *(const i32x4*)(wbase + tap * 2048);        // oc = lrow
        i32x4 w1v = *(const i32x4*)(wbase + tap * 2048 + 512); // oc = 32+lrow
#pragma unroll
        for (int t = 0; t < 3; ++t) {
            int off = (pixbase[t] + ky * 17 + kx) * 32 + kh * 16;
            i32x4 a = *(const i32x4*)(aimg[t] + aswz(off));
            acc[t][0] = __builtin_amdgcn_mfma_i32_32x32x32_i8(a, w0, acc[t][0], 0, 0, 0);
            acc[t][1] = __builtin_amdgcn_mfma_i32_32x32x32_i8(a, w1v, acc[t][1], 0, 0, 0);
        }
    }
    __syncthreads();   // all LDS A/W reads done -> act region reusable

    float bi[2], mm2[2], sc2[2], bb2[2];
#pragma unroll
    for (int h = 0; h < 2; ++h) {
        int oc = h * 32 + lrow;
        bi[h] = b2[oc]; mm2[h] = m2[oc];
        sc2[h] = g2[oc] / sqrtf(v2[oc] + 1e-5f); bb2[h] = be2[oc];
    }
#pragma unroll
    for (int t = 0; t < 3; ++t) {
        int mt = wave * 3 + t;
#pragma unroll
        for (int h = 0; h < 2; ++h) {
            int oc = h * 32 + lrow;
#pragma unroll
            for (int g = 0; g < 4; g++) {
                int qo = mt * 8 + kh + 2 * g;     // pool cell 0..287 (8 images)
                int imo = qo / 36, qqo = qo - imo * 36;
                float best = -2.f;
#pragma unroll
                for (int jj = 0; jj < 4; jj++) {
                    float z = (float)acc[t][h][g * 4 + jj] + bi[h];
                    float bn = (z - mm2[h]) * sc2[h] + bb2[h];
                    best = fmaxf(best, fsign(bn));
                }
                smem[imo * 2304 + oc * 36 + qqo] = (signed char)best;
            }
        }
    }
    __syncthreads();
    {
        const i32x4* s4o = (const i32x4*)smem;
        i32x4* dst = (i32x4*)(act2 + (size_t)b0 * 2304);
        for (int i = tid; i < 1152; i += 768) dst[i] = s4o[i];
    }
}

// K3: fc1 as LDS-tiled MFMA i8 GEMM 2048x1024x2304. (r31 verbatim)
#define K3A_SEG 2064                // 128*16 + 16 pad
#define K3B_SEG 1040                // 64*16 + 16 pad
#define K3_BOFF 16512               // 8 * 2064
__global__ __launch_bounds__(256) void k3_mfma(
        const signed char* __restrict__ act2, const signed char* __restrict__ wf1s,
        const float* __restrict__ bf1, const float* __restrict__ gf1,
        const float* __restrict__ bef1, const float* __restrict__ mf1,
        const float* __restrict__ vf1, signed char* __restrict__ act3) {
    __shared__ __align__(16) signed char s[K3_BOFF + 8 * K3B_SEG];  // 24832
    int tid = threadIdx.x;
    int bid = blockIdx.x;
    int tn = bid & 15, tm = bid >> 4;

    const signed char* Ab = act2 + (size_t)tm * 128 * 2304;
    const signed char* Bb = wf1s + (size_t)tn * 64 * 2304;
    size_t gA[4]; int lwA[4];
#pragma unroll
    for (int i = 0; i < 4; i++) {
        int e = tid + 256 * i, row = e >> 3, sg = (e + row) & 7;
        gA[i] = (size_t)row * 2304 + sg * 16;
        lwA[i] = sg * K3A_SEG + row * 16;
    }
    size_t gB[2]; int lwB[2];
#pragma unroll
    for (int i = 0; i < 2; i++) {
        int e = tid + 256 * i, row = e >> 3, sg = (e + row) & 7;
        gB[i] = (size_t)row * 2304 + sg * 16;
        lwB[i] = K3_BOFF + sg * K3B_SEG + row * 16;
    }

    i32x4 ra[4], rb[2];
#pragma unroll
    for (int i = 0; i < 4; i++) ra[i] = *(const i32x4*)(Ab + gA[i]);
#pragma unroll
    for (int i = 0; i < 2; i++) rb[i] = *(const i32x4*)(Bb + gB[i]);

    int l = tid & 63, wid = tid >> 6;
    int lrow = l & 31, kh = l >> 5;
    int raddrA = kh * K3A_SEG + (wid * 32 + lrow) * 16;
    int raddrB0 = K3_BOFF + kh * K3B_SEG + lrow * 16;
    int raddrB1 = raddrB0 + 32 * 16;

    i32x16 acc0 = {0};
    i32x16 acc1 = {0};
    for (int t = 0; t < 18; ++t) {
        if (t) __syncthreads();
#pragma unroll
        for (int i = 0; i < 4; i++) *(i32x4*)(s + lwA[i]) = ra[i];
#pragma unroll
        for (int i = 0; i < 2; i++) *(i32x4*)(s + lwB[i]) = rb[i];
        if (t < 17) {
            size_t ko = (size_t)(t + 1) * 128;
#pragma unroll
            for (int i = 0; i < 4; i++) ra[i] = *(const i32x4*)(Ab + gA[i] + ko);
#pragma unroll
            for (int i = 0; i < 2; i++) rb[i] = *(const i32x4*)(Bb + gB[i] + ko);
        }
        __syncthreads();
#pragma unroll
        for (int ks = 0; ks < 4; ++ks) {
            i32x4 a  = *(const i32x4*)(s + raddrA + ks * 2 * K3A_SEG);
            i32x4 b0 = *(const i32x4*)(s + raddrB0 + ks * 2 * K3B_SEG);
            i32x4 b1 = *(const i32x4*)(s + raddrB1 + ks * 2 * K3B_SEG);
            acc0 = __builtin_amdgcn_mfma_i32_32x32x32_i8(a, b0, acc0, 0, 0, 0);
            acc1 = __builtin_amdgcn_mfma_i32_32x32x32_i8(a, b1, acc1, 0, 0, 0);
        }
    }

    int col0 = tn * 64 + lrow;
    int col1 = col0 + 32;
    float bi0 = bf1[col0], m0 = mf1[col0];
    float sc0 = gf1[col0] / sqrtf(vf1[col0] + 1e-5f), bb0 = bef1[col0];
    float bi1 = bf1[col1], m1 = mf1[col1];
    float sc1 = gf1[col1] / sqrtf(vf1[col1] + 1e-5f), bb1 = bef1[col1];
    __syncthreads();   // K-loop reads of s done -> reuse as output tile [128][64]
#pragma unroll
    for (int r = 0; r < 16; r++) {
        int rowl = wid * 32 + (r & 3) + 8 * (r >> 2) + 4 * kh;
        float bn0 = ((float)acc0[r] + bi0 - m0) * sc0 + bb0;
        float bn1 = ((float)acc1[r] + bi1 - m1) * sc1 + bb1;
        s[rowl * 64 + lrow] = (signed char)fsign(bn0);
        s[rowl * 64 + lrow + 32] = (signed char)fsign(bn1);
    }
    __syncthreads();
    for (int i = tid; i < 512; i += 256) {
        int rl = i >> 2, c16 = i & 3;
        *(i32x4*)(act3 + (size_t)(tm * 128 + rl) * 1024 + tn * 64 + c16 * 16) =
            *(const i32x4*)(s + i * 16);
    }
}

// K4: fc2 (1024->10) + bias + BN + log_softmax. One wave per image. (unchanged)
__global__ void k4_fc2(const signed char* __restrict__ act3, const signed char* __restrict__ swf2,
                       const float* __restrict__ bf2, const float* __restrict__ gf2,
                       const float* __restrict__ bef2, const float* __restrict__ mf2,
                       const float* __restrict__ vf2, float* __restrict__ out) {
    int wid = (blockIdx.x * 256 + threadIdx.x) >> 6;
    int lane = threadIdx.x & 63;
    if (wid >= BATCH) return;
    const int* hd = (const int*)act3 + (size_t)wid * 256;
    const int* wd = (const int*)swf2;
    int acc[10];
#pragma unroll
    for (int o = 0; o < 10; o++) acc[o] = 0;
#pragma unroll
    for (int i = 0; i < 4; i++) {
        int k4 = i * 64 + lane;
        int hv = hd[k4];
#pragma unroll
        for (int o = 0; o < 10; o++)
            acc[o] = sdot4(hv, wd[o * 256 + k4], acc[o]);
    }
#pragma unroll
    for (int o = 0; o < 10; o++)
#pragma unroll
        for (int s = 32; s > 0; s >>= 1) acc[o] += __shfl_xor(acc[o], s);
    if (lane == 0) {
        float logit[10];
        float mx = -1e30f;
#pragma unroll
        for (int o = 0; o < 10; o++) {
            float z = (float)acc[o] + bf2[o];
            float bn = (z - mf2[o]) * (gf2[o] / sqrtf(vf2[o] + 1e-5f)) + bef2[o];
            logit[o] = bn;
            mx = fmaxf(mx, bn);
        }
        float s = 0.f;
#pragma unroll
        for (int o = 0; o < 10; o++) s += expf(logit[o] - mx);
        float lse = mx + logf(s);
#pragma unroll
        for (int o = 0; o < 10; o++) out[(size_t)wid * 10 + o] = logit[o] - lse;
    }
}

extern "C" void kernel_launch(void* const* d_in, const int* in_sizes, int n_in,
                              void* d_out, int out_size, void* d_ws, size_t ws_size,
                              hipStream_t stream) {
    const float* x   = (const float*)d_in[0];
    const float* w1  = (const float*)d_in[1];
    const float* b1  = (const float*)d_in[2];
    const float* g1  = (const float*)d_in[3];
    const float* be1 = (const float*)d_in[4];
    const float* m1  = (const float*)d_in[5];
    const float* v1  = (const float*)d_in[6];
    const float* w2  = (const float*)d_in[7];
    const float* b2  = (const float*)d_in[8];
    const float* g2  = (const float*)d_in[9];
    const float* be2 = (const float*)d_in[10];
    const float* m2  = (const float*)d_in[11];
    const float* v2  = (const float*)d_in[12];
    const float* wf1 = (const float*)d_in[13];
    const float* bf1 = (const float*)d_in[14];
    const float* gf1 = (const float*)d_in[15];
    const float* bef1= (const float*)d_in[16];
    const float* mf1 = (const float*)d_in[17];
    const float* vf1 = (const float*)d_in[18];
    const float* wf2 = (const float*)d_in[19];
    const float* bf2 = (const float*)d_in[20];
    const float* gf2 = (const float*)d_in[21];
    const float* bef2= (const float*)d_in[22];
    const float* mf2 = (const float*)d_in[23];
    const float* vf2 = (const float*)d_in[24];
    float* out = (float*)d_out;

    // ws layout (all int8)
    char* ws = (char*)d_ws;
    signed char* act1 = (signed char*)ws;                  // 2048*5408     = 11,075,584
    signed char* act2 = act1 + 11075584;                   // 2048*2304     =  4,718,592
    signed char* act3 = act2 + 4718592;                    // 2048*1024     =  2,097,152
    signed char* w2p  = act3 + 2097152;                    // 25*2*64*16    =     51,200
    signed char* wf1s = w2p + 51200;                       // 1024*2304     =  2,359,296
    signed char* wf2p = wf1s + 2359296;                    // 10*1024       =     10,240

    k1_prep<<<1024, 512, 0, stream>>>(x, w1, b1, g1, be1, m1, v1, w2, wf1, wf2,
                                      w2p, wf1s, wf2p, act1);

    k2_mfma<<<256, 768, 0, stream>>>(act1, w2p, b2, g2, be2, m2, v2, act2);

    k3_mfma<<<256, 256, 0, stream>>>(act2, wf1s, bf1, gf1, bef1, mf1, vf1, act3);

    k4_fc2<<<512, 256, 0, stream>>>(act3, wf2p, bf2, gf2, bef2, mf2, vf2, out);
}